// Round 8
// baseline (215.821 us; speedup 1.0000x reference)
//
#include <hip/hip_runtime.h>
#include <hip/hip_bf16.h>
#include <stdint.h>

typedef unsigned short u16;
typedef unsigned int   u32;
typedef __bf16  bf16x8 __attribute__((ext_vector_type(8)));
typedef float   f32x4  __attribute__((ext_vector_type(4)));
typedef float   f32x16 __attribute__((ext_vector_type(16)));

#define K_DIM  2048
#define N_E    16
#define HID    128
#define ODIM   64
#define NBATCH 8192
#define PART   (NBATCH * ODIM)

__device__ __forceinline__ u16 f2bf(float f) {
  u32 u = __builtin_bit_cast(u32, f);
  u32 r = (u + 0x7fffu + ((u >> 16) & 1u)) >> 16;   // RNE
  return (u16)r;
}
__device__ __forceinline__ void gl_lds16(const void* g, void* l) {
  __builtin_amdgcn_global_load_lds(
      (const __attribute__((address_space(1))) u32*)g,
      (__attribute__((address_space(3))) u32*)l, 16, 0, 0);
}
__device__ __forceinline__ bf16x8 ld16(const void* p) {
  return __builtin_bit_cast(bf16x8, *(const uint4*)p);
}
__device__ __forceinline__ f32x16 mfma32(bf16x8 va, bf16x8 vb, f32x16 c) {
  return __builtin_amdgcn_mfma_f32_32x32x16_bf16(va, vb, c, 0, 0, 0);
}

#define BAR()    __builtin_amdgcn_s_barrier()
#define WAITV8() asm volatile("s_waitcnt vmcnt(8)")
#define WAITV6() asm volatile("s_waitcnt vmcnt(6)")
#define WAITV0() asm volatile("s_waitcnt vmcnt(0)")

// ---------------- k_front: attn+cast (0..511) | W1 prep (512..2559) |
//                  W2 prep (2560..2623) -------------------------------------
__global__ __launch_bounds__(256) void k_front(
    const float* __restrict__ z, const float* __restrict__ Wa,
    const float* __restrict__ ba, const float* __restrict__ W1,
    const float* __restrict__ W2, u16* __restrict__ zb,
    float* __restrict__ attn, u16* __restrict__ W1T, u16* __restrict__ W2T) {
  const int b = blockIdx.x, tid = threadIdx.x;
  if (b >= 512) {
    if (b < 2560) {                              // W1 [16][2048][128] -> [n][k]
      int gid = (b - 512) * 256 + tid;
      int n  = gid & 2047;
      int k8 = gid >> 11;
      const float* src = W1 + (size_t)(n >> 7) * (K_DIM * HID) + (n & 127);
      int kb = k8 * 8;
      u32 o0, o1, o2, o3;
      o0 = (u32)f2bf(src[(size_t)(kb+0)*HID]) | ((u32)f2bf(src[(size_t)(kb+1)*HID]) << 16);
      o1 = (u32)f2bf(src[(size_t)(kb+2)*HID]) | ((u32)f2bf(src[(size_t)(kb+3)*HID]) << 16);
      o2 = (u32)f2bf(src[(size_t)(kb+4)*HID]) | ((u32)f2bf(src[(size_t)(kb+5)*HID]) << 16);
      o3 = (u32)f2bf(src[(size_t)(kb+6)*HID]) | ((u32)f2bf(src[(size_t)(kb+7)*HID]) << 16);
      *(uint4*)(W1T + (size_t)n * K_DIM + kb) = make_uint4(o0, o1, o2, o3);
    } else {                                     // W2 [2048][64] -> [o][r]
      int gid = (b - 2560) * 256 + tid;
      int o  = gid & 63;
      int rb = (gid >> 6) * 8;
      u32 o0, o1, o2, o3;
      o0 = (u32)f2bf(W2[(size_t)(rb+0)*64 + o]) | ((u32)f2bf(W2[(size_t)(rb+1)*64 + o]) << 16);
      o1 = (u32)f2bf(W2[(size_t)(rb+2)*64 + o]) | ((u32)f2bf(W2[(size_t)(rb+3)*64 + o]) << 16);
      o2 = (u32)f2bf(W2[(size_t)(rb+4)*64 + o]) | ((u32)f2bf(W2[(size_t)(rb+5)*64 + o]) << 16);
      o3 = (u32)f2bf(W2[(size_t)(rb+6)*64 + o]) | ((u32)f2bf(W2[(size_t)(rb+7)*64 + o]) << 16);
      *(uint4*)(W2T + (size_t)o * K_DIM + rb) = make_uint4(o0, o1, o2, o3);
    }
    return;
  }
  const int l = tid & 63, w = tid >> 6;
  const int r0 = b * 16 + w * 4;
  const float* zp = z + (size_t)r0 * K_DIM;
  u16* zbp = zb + (size_t)r0 * K_DIM;

  float bav[16];
#pragma unroll
  for (int e = 0; e < 16; ++e) bav[e] = ba[e];

  float acc[4][16] = {};
#pragma unroll
  for (int i = 0; i < 8; ++i) {
    const int kb = i * 256 + l * 4;
    float zrf[4][4];
#pragma unroll
    for (int r = 0; r < 4; ++r) {
      float4 v = *(const float4*)(zp + (size_t)r * K_DIM + kb);
      zrf[r][0] = v.x; zrf[r][1] = v.y; zrf[r][2] = v.z; zrf[r][3] = v.w;
      uint2 p;
      p.x = (u32)f2bf(v.x) | ((u32)f2bf(v.y) << 16);
      p.y = (u32)f2bf(v.z) | ((u32)f2bf(v.w) << 16);
      *(uint2*)(zbp + (size_t)r * K_DIM + kb) = p;
    }
#pragma unroll
    for (int kk = 0; kk < 4; ++kk) {
      const float4* wrow = (const float4*)(Wa + (size_t)(kb + kk) * 16);
      float wv[16];
#pragma unroll
      for (int j = 0; j < 4; ++j) {
        float4 u = wrow[j];
        wv[j*4+0] = u.x; wv[j*4+1] = u.y; wv[j*4+2] = u.z; wv[j*4+3] = u.w;
      }
#pragma unroll
      for (int r = 0; r < 4; ++r)
#pragma unroll
        for (int e = 0; e < 16; ++e)
          acc[r][e] = fmaf(zrf[r][kk], wv[e], acc[r][e]);
    }
  }
#pragma unroll
  for (int s = 1; s < 64; s <<= 1)
#pragma unroll
    for (int r = 0; r < 4; ++r)
#pragma unroll
      for (int e = 0; e < 16; ++e)
        acc[r][e] += __shfl_xor(acc[r][e], s, 64);
#pragma unroll
  for (int r = 0; r < 4; ++r) {
    float p[16], m = -1e30f, ssum = 0.f;
#pragma unroll
    for (int e = 0; e < 16; ++e) { p[e] = acc[r][e] + bav[e]; m = fmaxf(m, p[e]); }
#pragma unroll
    for (int e = 0; e < 16; ++e) { p[e] = __expf(p[e] - m); ssum += p[e]; }
    float inv = 1.0f / ssum;
    float v = p[0] * inv;
#pragma unroll
    for (int e = 1; e < 16; ++e) { float pe = p[e] * inv; v = (l == e) ? pe : v; }
    if (l < 16) attn[(size_t)(r0 + r) * 16 + l] = v;
  }
}

// ---------------- GEMM1+2 fused, 32x32x16 MFMA -------------------------------
// 256x256 tile, BK=64, 8 waves (2M x 4N), per-wave 128x64 = 4 rowfrags x 2 colfrags.
// ph1: rowfrags 0-1 (A1 region) + all B; ph2: rowfrags 2-3 (A2). B regs live
// across both phases. Stage/vmcnt schedule identical to R6/R7 (audit carries).
#define RDAB1(L)                                                          \
  do {                                                                    \
    _Pragma("unroll")                                                     \
    for (int ks = 0; ks < 4; ++ks) {                                      \
      const int sw = ((2 * ks + h) ^ (l & 7)) << 4;                       \
      a[0][ks] = ld16((L) + abase + sw);                                  \
      a[1][ks] = ld16((L) + abase + 4096 + sw);                           \
      b[0][ks] = ld16((L) + bbase + sw);                                  \
      b[1][ks] = ld16((L) + bbase + 16384 + sw);                          \
    }                                                                     \
  } while (0)
#define RDA2(L)                                                           \
  do {                                                                    \
    _Pragma("unroll")                                                     \
    for (int ks = 0; ks < 4; ++ks) {                                      \
      const int sw = ((2 * ks + h) ^ (l & 7)) << 4;                       \
      a[0][ks] = ld16((L) + 16384 + abase + sw);                          \
      a[1][ks] = ld16((L) + 16384 + abase + 4096 + sw);                   \
    }                                                                     \
  } while (0)
#define MM(P)                                                             \
  do {                                                                    \
    __builtin_amdgcn_s_setprio(1);                                        \
    _Pragma("unroll")                                                     \
    for (int ks = 0; ks < 4; ++ks)                                        \
      _Pragma("unroll")                                                   \
      for (int rfp = 0; rfp < 2; ++rfp)                                   \
        _Pragma("unroll")                                                 \
        for (int cf = 0; cf < 2; ++cf)                                    \
          acc[(P) * 2 + rfp][cf] =                                        \
              mfma32(a[rfp][ks], b[cf][ks], acc[(P) * 2 + rfp][cf]);      \
    __builtin_amdgcn_s_setprio(0);                                        \
  } while (0)

__global__ __launch_bounds__(512, 2) void k_gemm1f(
    const u16* __restrict__ A, const u16* __restrict__ BT,
    const float* __restrict__ bias1, const float* __restrict__ attn,
    const u16* __restrict__ W2T, float* __restrict__ partials) {
  extern __shared__ char lds[];                  // 131072 B
  const int tid = threadIdx.x;
  const int l = tid & 63, w = tid >> 6;
  const int wm = w >> 2, wn = w & 3;
  const int lr = l & 31, h = l >> 5;

  const int bid = blockIdx.x;
  const int swz = (bid & 7) * 32 + (bid >> 3);
  const int bm = swz >> 3, bn = swz & 7;
  const size_t brow = (size_t)bm * 256;
  const int bcol = bn * 256;

  // staging sources (pre-swizzled global, linear LDS dest)
  const int slot = (tid & 7) ^ ((tid >> 3) & 7);
  const u16* sA0 = A + (brow + 0 * 128 + (tid >> 3)) * K_DIM + slot * 8;
  const u16* sA1 = A + (brow + 1 * 128 + (tid >> 3)) * K_DIM + slot * 8;
  const int bq0 = (tid >> 3) >> 5;
  const int bcr = (tid >> 3) & 31;
  const u16* sB0 = BT + (size_t)(bcol + (0 + bq0) * 64 + bcr) * K_DIM + slot * 8;
  const u16* sB1 = BT + (size_t)(bcol + (2 + bq0) * 64 + bcr) * K_DIM + slot * 8;

  char* const ldsw = lds + w * 1024;
  auto stA = [&](int p, int kt, int buf) {
    char* d = ldsw + buf * 65536 + p * 16384;
    gl_lds16(sA0 + (size_t)p * (64 * K_DIM) + kt * 64, d);
    gl_lds16(sA1 + (size_t)p * (64 * K_DIM) + kt * 64, d + 8192);
  };
  auto stB = [&](int q, int kt, int buf) {
    char* d = ldsw + buf * 65536 + 32768 + q * 16384;
    gl_lds16(sB0 + (size_t)q * (32 * K_DIM) + kt * 64, d);
    gl_lds16(sB1 + (size_t)q * (32 * K_DIM) + kt * 64, d + 8192);
  };

  // fragment read bases: A row = wm*128 + P*64 + rfp*32 + lr; B col = wn*64 + cf*32 + lr
  const int abase = wm * 8192 + lr * 128;        // + rfp*4096 (+16384 for A2)
  const int bbase = 32768 + wn * 4096 + lr * 128;  // + cf*16384

  f32x16 acc[4][2] = {};
  bf16x8 a[2][4], b[2][4];

  // prologue (14 loads)
  stA(0, 0, 0); stB(0, 0, 0); stB(1, 0, 0);
  stA(1, 0, 0);
  stA(0, 1, 1); stB(0, 1, 1); stB(1, 1, 1);
  WAITV8(); BAR();

  const char* const L0 = lds;
  const char* const L1 = lds + 65536;
  for (int t = 0; t < 30; t += 2) {
    RDAB1(L0);
    stA(1, t + 1, 1);
    BAR(); MM(0); WAITV8(); BAR();
    RDA2(L0);
    stA(0, t + 2, 0); stB(0, t + 2, 0); stB(1, t + 2, 0);
    BAR(); MM(1); WAITV8(); BAR();
    RDAB1(L1);
    stA(1, t + 2, 0);
    BAR(); MM(0); WAITV8(); BAR();
    RDA2(L1);
    stA(0, t + 3, 1); stB(0, t + 3, 1); stB(1, t + 3, 1);
    BAR(); MM(1); WAITV8(); BAR();
  }
  // epilogue tiles 30 (buf0), 31 (buf1); W2 slice staged into dead buf0-B
  {
    RDAB1(L0);
    stA(1, 31, 1);
    BAR(); MM(0); WAITV8(); BAR();
    RDA2(L0);
    {  // W2 slice: LDS row o (512B), slot s holds src slot s^(o&7); dest linear
      const int so = tid >> 5;
#pragma unroll
      for (int rnd = 0; rnd < 4; ++rnd) {
        const int o = rnd * 16 + so;
        gl_lds16(W2T + (size_t)o * K_DIM + bcol + (((tid & 31) ^ (so & 7)) << 3),
                 lds + 32768 + rnd * 8192 + w * 1024);
      }
    }
    BAR(); MM(1); WAITV6(); BAR();
    RDAB1(L1);
    BAR(); MM(0); WAITV0(); BAR();
    RDA2(L1);
    BAR(); MM(1);
  }
  BAR();                                         // all buf1 reads complete

  // ---- fused GEMM2: two half-passes through hL = lds+65536 (64 KB),
  //      W2 slice at wL = lds+32768 ----
  char* const hL = lds + 65536;
  const char* const wL = lds + 32768;
  const int eg = bn * 2 + (wn >> 1);
  const int lrow2 = (w & 3) * 32 + lr;           // GEMM2 row (within half)
  const int o2 = (w >> 2) * 32 + lr;             // GEMM2 col

  for (int hp = 0; hp < 2; ++hp) {
    if (wm == hp) {
      // write h' = attn*relu(acc+b1): rows (local) rf*32 + (r&3)+8*(r>>2)+4h
#pragma unroll
      for (int rf = 0; rf < 4; ++rf) {
#pragma unroll
        for (int cf = 0; cf < 2; ++cf) {
          const int col = wn * 64 + cf * 32 + lr;
          const float bias = bias1[eg * 128 + (col & 127)];
#pragma unroll
          for (int r = 0; r < 16; ++r) {
            const int lrow = rf * 32 + (r & 3) + 8 * (r >> 2) + 4 * h;
            float v = acc[rf][cf][r] + bias;
            v = fmaxf(v, 0.f) * attn[(brow + wm * 128 + lrow) * 16 + eg];
            *(u16*)(hL + lrow * 512 + ((((col >> 3) ^ (lrow & 7))) << 4)
                    + (col & 7) * 2) = f2bf(v);
          }
        }
      }
    }
    BAR();
    f32x16 acc2 = {};
#pragma unroll
    for (int ks = 0; ks < 16; ++ks) {
      const int s32 = ks * 2 + h;
      bf16x8 a2 = ld16(hL + lrow2 * 512 + ((s32 ^ (lr & 7)) << 4));
      bf16x8 bb = ld16(wL + o2 * 512 + ((s32 ^ (lr & 7)) << 4));
      acc2 = mfma32(a2, bb, acc2);
    }
#pragma unroll
    for (int r = 0; r < 16; ++r) {
      const int grow = hp * 128 + (w & 3) * 32 + (r & 3) + 8 * (r >> 2) + 4 * h;
      partials[(size_t)bn * PART + (brow + grow) * 64 + o2] = acc2[r];
    }
    BAR();                                       // before next hp overwrites hL
  }
}

// ---------------- k_back: out = sum_j partials[j] + attn @ b2 ----------------
__global__ __launch_bounds__(256) void k_back(
    const float* __restrict__ partials, const float* __restrict__ attn,
    const float* __restrict__ b2, float* __restrict__ out) {
  const int idx = blockIdx.x * 256 + threadIdx.x;   // 262144
  const int m = idx >> 5;
  const int o = (idx & 31) * 2;
  float s0 = 0.f, s1 = 0.f;
#pragma unroll
  for (int j = 0; j < 8; ++j) {
    float2 p = *(const float2*)(partials + (size_t)j * PART + (size_t)m * 64 + o);
    s0 += p.x; s1 += p.y;
  }
  const float* ar = attn + (size_t)m * 16;
#pragma unroll
  for (int e = 0; e < 16; ++e) {
    const float av = ar[e];
    s0 = fmaf(av, b2[e * 64 + o], s0);
    s1 = fmaf(av, b2[e * 64 + o + 1], s1);
  }
  *(float2*)(out + (size_t)m * 64 + o) = make_float2(s0, s1);
}

// ---------------- launch -----------------------------------------------------
extern "C" void kernel_launch(void* const* d_in, const int* in_sizes, int n_in,
                              void* d_out, int out_size, void* d_ws, size_t ws_size,
                              hipStream_t stream) {
  (void)in_sizes; (void)n_in; (void)out_size; (void)ws_size;
  const float* z  = (const float*)d_in[0];
  const float* W1 = (const float*)d_in[1];
  const float* b1 = (const float*)d_in[2];
  const float* W2 = (const float*)d_in[3];
  const float* b2 = (const float*)d_in[4];
  const float* Wa = (const float*)d_in[5];
  const float* ba = (const float*)d_in[6];
  float* out = (float*)d_out;
  char* ws = (char*)d_ws;
  u16*   W1T      = (u16*)(ws);                 // 8 MB
  u16*   W2T      = (u16*)(ws + 8388608);       // 256 KB
  u16*   zb       = (u16*)(ws + 8716288);       // 32 MB
  float* attn     = (float*)(ws + 42270720);    // 512 KB
  float* partials = (float*)(ws + 42795008);    // 16 MB

  (void)hipFuncSetAttribute((const void*)k_gemm1f,
                            hipFuncAttributeMaxDynamicSharedMemorySize, 131072);

  k_front <<<2624, 256, 0, stream>>>(z, Wa, ba, W1, W2, zb, attn, W1T, W2T);
  k_gemm1f<<<256,  512, 131072, stream>>>(zb, W1T, b1, attn, W2T, partials);
  k_back  <<<1024, 256, 0, stream>>>(partials, attn, b2, out);
}

// Round 9
// 112.720 us; speedup vs baseline: 1.9147x; 1.9147x over previous
//
#include <hip/hip_runtime.h>
#include <hip/hip_bf16.h>
#include <stdint.h>

typedef unsigned short u16;
typedef unsigned int   u32;
typedef __bf16  bf16x8 __attribute__((ext_vector_type(8)));
typedef float   f32x4  __attribute__((ext_vector_type(4)));

#define K_DIM  2048
#define N_E    16
#define HID    128
#define ODIM   64
#define NBATCH 8192
#define PART   (NBATCH * ODIM)

__device__ __forceinline__ u16 f2bf(float f) {
  u32 u = __builtin_bit_cast(u32, f);
  u32 r = (u + 0x7fffu + ((u >> 16) & 1u)) >> 16;   // RNE
  return (u16)r;
}
__device__ __forceinline__ float bf2f(u32 h) {
  return __builtin_bit_cast(float, h << 16);
}
__device__ __forceinline__ void gl_lds16(const void* g, void* l) {
  __builtin_amdgcn_global_load_lds(
      (const __attribute__((address_space(1))) u32*)g,
      (__attribute__((address_space(3))) u32*)l, 16, 0, 0);
}
__device__ __forceinline__ bf16x8 ld16(const void* p) {
  return __builtin_bit_cast(bf16x8, *(const uint4*)p);
}

#define BAR()    __builtin_amdgcn_s_barrier()
#define WAITV8() asm volatile("s_waitcnt vmcnt(8)")
#define WAITV6() asm volatile("s_waitcnt vmcnt(6)")
#define WAITV0() asm volatile("s_waitcnt vmcnt(0)")

// ---------------- k_front: attn+cast (0..511) | W1 prep (512..2559) |
//                  W2 prep (2560..2623) -------------------------------------
__global__ __launch_bounds__(256) void k_front(
    const float* __restrict__ z, const float* __restrict__ Wa,
    const float* __restrict__ ba, const float* __restrict__ W1,
    const float* __restrict__ W2, u16* __restrict__ zb,
    float* __restrict__ attn, u16* __restrict__ W1T, u16* __restrict__ W2T) {
  const int b = blockIdx.x, tid = threadIdx.x;
  if (b >= 512) {
    if (b < 2560) {                              // W1 [16][2048][128] -> [n][k]
      int gid = (b - 512) * 256 + tid;
      int n  = gid & 2047;
      int k8 = gid >> 11;
      const float* src = W1 + (size_t)(n >> 7) * (K_DIM * HID) + (n & 127);
      int kb = k8 * 8;
      u32 o0, o1, o2, o3;
      o0 = (u32)f2bf(src[(size_t)(kb+0)*HID]) | ((u32)f2bf(src[(size_t)(kb+1)*HID]) << 16);
      o1 = (u32)f2bf(src[(size_t)(kb+2)*HID]) | ((u32)f2bf(src[(size_t)(kb+3)*HID]) << 16);
      o2 = (u32)f2bf(src[(size_t)(kb+4)*HID]) | ((u32)f2bf(src[(size_t)(kb+5)*HID]) << 16);
      o3 = (u32)f2bf(src[(size_t)(kb+6)*HID]) | ((u32)f2bf(src[(size_t)(kb+7)*HID]) << 16);
      *(uint4*)(W1T + (size_t)n * K_DIM + kb) = make_uint4(o0, o1, o2, o3);
    } else {                                     // W2 [2048][64] -> [o][r]
      int gid = (b - 2560) * 256 + tid;
      int o  = gid & 63;
      int rb = (gid >> 6) * 8;
      u32 o0, o1, o2, o3;
      o0 = (u32)f2bf(W2[(size_t)(rb+0)*64 + o]) | ((u32)f2bf(W2[(size_t)(rb+1)*64 + o]) << 16);
      o1 = (u32)f2bf(W2[(size_t)(rb+2)*64 + o]) | ((u32)f2bf(W2[(size_t)(rb+3)*64 + o]) << 16);
      o2 = (u32)f2bf(W2[(size_t)(rb+4)*64 + o]) | ((u32)f2bf(W2[(size_t)(rb+5)*64 + o]) << 16);
      o3 = (u32)f2bf(W2[(size_t)(rb+6)*64 + o]) | ((u32)f2bf(W2[(size_t)(rb+7)*64 + o]) << 16);
      *(uint4*)(W2T + (size_t)o * K_DIM + rb) = make_uint4(o0, o1, o2, o3);
    }
    return;
  }
  const int l = tid & 63, w = tid >> 6;
  const int r0 = b * 16 + w * 4;
  const float* zp = z + (size_t)r0 * K_DIM;
  u16* zbp = zb + (size_t)r0 * K_DIM;

  float bav[16];
#pragma unroll
  for (int e = 0; e < 16; ++e) bav[e] = ba[e];

  float acc[4][16] = {};
#pragma unroll
  for (int i = 0; i < 8; ++i) {
    const int kb = i * 256 + l * 4;
    float zrf[4][4];
#pragma unroll
    for (int r = 0; r < 4; ++r) {
      float4 v = *(const float4*)(zp + (size_t)r * K_DIM + kb);
      zrf[r][0] = v.x; zrf[r][1] = v.y; zrf[r][2] = v.z; zrf[r][3] = v.w;
      uint2 p;
      p.x = (u32)f2bf(v.x) | ((u32)f2bf(v.y) << 16);
      p.y = (u32)f2bf(v.z) | ((u32)f2bf(v.w) << 16);
      *(uint2*)(zbp + (size_t)r * K_DIM + kb) = p;
    }
#pragma unroll
    for (int kk = 0; kk < 4; ++kk) {
      const float4* wrow = (const float4*)(Wa + (size_t)(kb + kk) * 16);
      float wv[16];
#pragma unroll
      for (int j = 0; j < 4; ++j) {
        float4 u = wrow[j];
        wv[j*4+0] = u.x; wv[j*4+1] = u.y; wv[j*4+2] = u.z; wv[j*4+3] = u.w;
      }
#pragma unroll
      for (int r = 0; r < 4; ++r)
#pragma unroll
        for (int e = 0; e < 16; ++e)
          acc[r][e] = fmaf(zrf[r][kk], wv[e], acc[r][e]);
    }
  }
#pragma unroll
  for (int s = 1; s < 64; s <<= 1)
#pragma unroll
    for (int r = 0; r < 4; ++r)
#pragma unroll
      for (int e = 0; e < 16; ++e)
        acc[r][e] += __shfl_xor(acc[r][e], s, 64);
#pragma unroll
  for (int r = 0; r < 4; ++r) {
    float p[16], m = -1e30f, ssum = 0.f;
#pragma unroll
    for (int e = 0; e < 16; ++e) { p[e] = acc[r][e] + bav[e]; m = fmaxf(m, p[e]); }
#pragma unroll
    for (int e = 0; e < 16; ++e) { p[e] = __expf(p[e] - m); ssum += p[e]; }
    float inv = 1.0f / ssum;
    float v = p[0] * inv;
#pragma unroll
    for (int e = 1; e < 16; ++e) { float pe = p[e] * inv; v = (l == e) ? pe : v; }
    if (l < 16) attn[(size_t)(r0 + r) * 16 + l] = v;
  }
}

// ---------------- GEMM1+2 fused: 256x256 K-loop (16x16x32), in-LDS GEMM2 ----
#define RDA(BASE)                                                         \
  do {                                                                    \
    _Pragma("unroll")                                                     \
    for (int rf = 0; rf < 4; ++rf) {                                      \
      a[rf][0] = ld16((BASE) + aro + rf * 2048 + sw0);                    \
      a[rf][1] = ld16((BASE) + aro + rf * 2048 + sw1);                    \
    }                                                                     \
  } while (0)
#define RDB(BASE, OFF)                                                    \
  do {                                                                    \
    _Pragma("unroll")                                                     \
    for (int cf = 0; cf < 2; ++cf) {                                      \
      b[(OFF) + cf][0] = ld16((BASE) + bro + cf * 2048 + sw0);            \
      b[(OFF) + cf][1] = ld16((BASE) + bro + cf * 2048 + sw1);            \
    }                                                                     \
  } while (0)
#define MM32(RO)                                                          \
  do {                                                                    \
    __builtin_amdgcn_s_setprio(1);                                        \
    _Pragma("unroll")                                                     \
    for (int kh = 0; kh < 2; ++kh)                                        \
      _Pragma("unroll")                                                   \
      for (int rf = 0; rf < 4; ++rf)                                      \
        _Pragma("unroll")                                                 \
        for (int cf = 0; cf < 4; ++cf)                                    \
          acc[(RO) + rf][cf] =                                            \
              __builtin_amdgcn_mfma_f32_16x16x32_bf16(                    \
                  a[rf][kh], b[cf][kh], acc[(RO) + rf][cf], 0, 0, 0);     \
    __builtin_amdgcn_s_setprio(0);                                        \
  } while (0)

__global__ __launch_bounds__(512, 2) void k_gemm1f(
    const u16* __restrict__ A, const u16* __restrict__ BT,
    const float* __restrict__ bias1, const float* __restrict__ attn,
    const u16* __restrict__ W2T, u16* __restrict__ partials) {
  extern __shared__ char lds[];                  // 131072 B
  const int tid = threadIdx.x;
  const int l = tid & 63, w = tid >> 6;
  const int wm = w >> 2, wn = w & 3;
  const int rl = l & 15, kq = l >> 4;

  const int bid = blockIdx.x;
  const int swz = (bid & 7) * 32 + (bid >> 3);   // 256 % 8 == 0: bijective
  const int bm = swz >> 3, bn = swz & 7;
  const size_t brow = (size_t)bm * 256;
  const int bcol = bn * 256;

  // ---- staging source pointers (pre-swizzled global, linear LDS dest) ----
  const int slot = (tid & 7) ^ ((tid >> 3) & 7);
  const u16* sA0 = A + (brow + 0 * 128 + (tid >> 3)) * K_DIM + slot * 8;
  const u16* sA1 = A + (brow + 1 * 128 + (tid >> 3)) * K_DIM + slot * 8;
  const int bq0 = (tid >> 3) >> 5;
  const int bcr = (tid >> 3) & 31;
  const u16* sB0 = BT + (size_t)(bcol + (0 + bq0) * 64 + bcr) * K_DIM + slot * 8;
  const u16* sB1 = BT + (size_t)(bcol + (2 + bq0) * 64 + bcr) * K_DIM + slot * 8;

  char* const ldsw = lds + w * 1024;
  auto stA = [&](int p, int kt, int buf) {
    char* d = ldsw + buf * 65536 + p * 16384;
    gl_lds16(sA0 + (size_t)p * (64 * K_DIM) + kt * 64, d);
    gl_lds16(sA1 + (size_t)p * (64 * K_DIM) + kt * 64, d + 8192);
  };
  auto stB = [&](int q, int kt, int buf) {
    char* d = ldsw + buf * 65536 + 32768 + q * 16384;
    gl_lds16(sB0 + (size_t)q * (32 * K_DIM) + kt * 64, d);
    gl_lds16(sB1 + (size_t)q * (32 * K_DIM) + kt * 64, d + 8192);
  };

  const int sw0 = ((kq ^ (rl & 7)) << 4);
  const int sw1 = (((4 + kq) ^ (rl & 7)) << 4);
  const int aro = (rl + wm * 64) * 128;
  const int bro = (wn * 32 + rl) * 128;

  f32x4  acc[8][4] = {};
  bf16x8 a[4][2], b[4][2];

  // ---- prologue ----
  stA(0, 0, 0); stB(0, 0, 0); stB(1, 0, 0);
  stA(1, 0, 0);
  stA(0, 1, 1); stB(0, 1, 1); stB(1, 1, 1);
  WAITV8(); BAR();

  const char* const L0 = lds;
  const char* const L1 = lds + 65536;
  for (int t = 0; t < 30; t += 2) {
    RDA(L0); RDB(L0 + 32768, 0); RDB(L0 + 49152, 2);
    stA(1, t + 1, 1);
    BAR(); MM32(0); WAITV8(); BAR();
    RDA(L0 + 16384);
    stA(0, t + 2, 0); stB(0, t + 2, 0); stB(1, t + 2, 0);
    BAR(); MM32(4); WAITV8(); BAR();
    RDA(L1); RDB(L1 + 32768, 0); RDB(L1 + 49152, 2);
    stA(1, t + 2, 0);
    BAR(); MM32(0); WAITV8(); BAR();
    RDA(L1 + 16384);
    stA(0, t + 3, 1); stB(0, t + 3, 1); stB(1, t + 3, 1);
    BAR(); MM32(4); WAITV8(); BAR();
  }
  // ---- epilogue: tiles 30 (buf0), 31 (buf1); W2 slice into dead buf0-B ----
  {
    RDA(L0); RDB(L0 + 32768, 0); RDB(L0 + 49152, 2);
    stA(1, 31, 1);
    BAR(); MM32(0); WAITV8(); BAR();
    RDA(L0 + 16384);
    // stage W2 slice: lds[32768 + o*512 + s*16] = W2T[o][bcol + (s^(o&7))*8]
    {
      const int so = tid >> 5, ss = tid & 31;
#pragma unroll
      for (int rnd = 0; rnd < 4; ++rnd) {
        const int o = rnd * 16 + so;
        gl_lds16(W2T + (size_t)o * K_DIM + bcol + ((ss ^ (o & 7)) << 3),
                 ldsw + 32768 + rnd * 8192 + (tid & 63) * 16
                 - (w * 1024) + ((tid >> 6) * 1024));
      }
    }
    BAR(); MM32(4); WAITV6(); BAR();
    RDA(L1); RDB(L1 + 32768, 0); RDB(L1 + 49152, 2);
    BAR(); MM32(0); WAITV0(); BAR();
    RDA(L1 + 16384);
    BAR(); MM32(4);
  }
  BAR();                                         // all buf1 reads complete

  // ---- fused GEMM2: h' tile (bf16, swizzled) in [65536,131072),
  //      W2 slice in [32768,65536); two half-passes over acc rows ----
  const int eg = bn * 2 + (wn >> 1);
  const int egb = eg * 128;
  char* const hL = lds + 65536;
  const char* const wL = lds + 32768;

#pragma unroll
  for (int half = 0; half < 2; ++half) {
    // write h' = attn*relu(acc+b1) for acc rows [half*4, half*4+4)
#pragma unroll
    for (int rf = 0; rf < 4; ++rf) {
      const int lrowb = wm * 64 + rf * 16 + kq * 4;
      const size_t mb = brow + wm * 128 + half * 64 + rf * 16 + kq * 4;
#pragma unroll
      for (int cf = 0; cf < 4; ++cf) {
        const int col = wn * 64 + cf * 16 + rl;
        const float bias = bias1[egb + ((wn & 1) * 64 + cf * 16 + rl)];
#pragma unroll
        for (int i = 0; i < 4; ++i) {
          const int lrow = lrowb + i;
          float v = acc[half * 4 + rf][cf][i] + bias;
          v = fmaxf(v, 0.f) * attn[(mb + i) * 16 + eg];
          *(u16*)(hL + lrow * 512 + (((col >> 3) ^ (lrow & 7)) << 4)
                  + (col & 7) * 2) = f2bf(v);
        }
      }
    }
    BAR();
    // MFMA2: rows lrow in [w*16, w*16+16), K = 256 h'-cols, out 16x64
    f32x4 acc2[4] = {};
#pragma unroll
    for (int ks = 0; ks < 8; ++ks) {
      const int sl = ((ks * 4 + kq) ^ (rl & 7)) << 4;
      bf16x8 a2 = ld16(hL + (w * 16 + rl) * 512 + sl);
#pragma unroll
      for (int cf = 0; cf < 4; ++cf) {
        bf16x8 bb = ld16(wL + (cf * 16 + rl) * 512 + sl);
        acc2[cf] = __builtin_amdgcn_mfma_f32_16x16x32_bf16(a2, bb, acc2[cf], 0, 0, 0);
      }
    }
    // store partials (bf16): m = brow + half*64 + (lrow>>6)*128 + (lrow&63)
    const int lr0 = w * 16 + kq * 4;
#pragma unroll
    for (int cf = 0; cf < 4; ++cf) {
      const int o = cf * 16 + rl;
#pragma unroll
      for (int i = 0; i < 4; ++i) {
        const int lrow = lr0 + i;
        const size_t m = brow + half * 64 + (size_t)(lrow >> 6) * 128 + (lrow & 63);
        partials[(size_t)bn * PART + m * 64 + o] = f2bf(acc2[cf][i]);
      }
    }
    BAR();                                       // before next half overwrites hL
  }
}

// ---------------- k_back: out = sum_j bf16(partials[j]) + attn @ b2 ----------
__global__ __launch_bounds__(256) void k_back(
    const u16* __restrict__ partials, const float* __restrict__ attn,
    const float* __restrict__ b2, float* __restrict__ out) {
  const int idx = blockIdx.x * 256 + threadIdx.x;   // 131072
  const int m = idx >> 4;
  const int o = (idx & 15) * 4;
  float s0 = 0.f, s1 = 0.f, s2 = 0.f, s3 = 0.f;
#pragma unroll
  for (int j = 0; j < 8; ++j) {
    uint2 p = *(const uint2*)(partials + (size_t)j * PART + (size_t)m * 64 + o);
    s0 += bf2f(p.x & 0xffffu); s1 += bf2f(p.x >> 16);
    s2 += bf2f(p.y & 0xffffu); s3 += bf2f(p.y >> 16);
  }
  const float* ar = attn + (size_t)m * 16;
#pragma unroll
  for (int e = 0; e < 16; ++e) {
    const float av = ar[e];
    s0 = fmaf(av, b2[e * 64 + o + 0], s0);
    s1 = fmaf(av, b2[e * 64 + o + 1], s1);
    s2 = fmaf(av, b2[e * 64 + o + 2], s2);
    s3 = fmaf(av, b2[e * 64 + o + 3], s3);
  }
  *(float4*)(out + (size_t)m * 64 + o) = make_float4(s0, s1, s2, s3);
}

// ---------------- launch -----------------------------------------------------
extern "C" void kernel_launch(void* const* d_in, const int* in_sizes, int n_in,
                              void* d_out, int out_size, void* d_ws, size_t ws_size,
                              hipStream_t stream) {
  (void)in_sizes; (void)n_in; (void)out_size; (void)ws_size;
  const float* z  = (const float*)d_in[0];
  const float* W1 = (const float*)d_in[1];
  const float* b1 = (const float*)d_in[2];
  const float* W2 = (const float*)d_in[3];
  const float* b2 = (const float*)d_in[4];
  const float* Wa = (const float*)d_in[5];
  const float* ba = (const float*)d_in[6];
  float* out = (float*)d_out;
  char* ws = (char*)d_ws;
  u16*   W1T      = (u16*)(ws);                 // 8 MB
  u16*   W2T      = (u16*)(ws + 8388608);       // 256 KB
  u16*   zb       = (u16*)(ws + 8716288);       // 32 MB
  float* attn     = (float*)(ws + 42270720);    // 512 KB
  u16*   partials = (u16*)(ws + 42795008);      // 8 MB (bf16)

  (void)hipFuncSetAttribute((const void*)k_gemm1f,
                            hipFuncAttributeMaxDynamicSharedMemorySize, 131072);

  k_front <<<2624, 256, 0, stream>>>(z, Wa, ba, W1, W2, zb, attn, W1T, W2T);
  k_gemm1f<<<256,  512, 131072, stream>>>(zb, W1T, b1, attn, W2T, partials);
  k_back  <<<512,  256, 0, stream>>>(partials, attn, b2, out);
}